// Round 10
// baseline (197.685 us; speedup 1.0000x reference)
//
#include <hip/hip_runtime.h>
#include <hip/hip_bf16.h>
#include <math.h>

// Problem constants
#define BATCH 4
#define CIN   256
#define HH    64
#define WW    64
#define HW    4096      // HH*WW
#define COUT  64
#define KK    7
#define NTAP  49
#define NSEG  16        // j-segments in qk_stats (256 cols each)

// exp(d/8) == exp2(d * (log2e/8)); fold scale into bf16 q
#define QSCALE 0.18033688011112042f

typedef __attribute__((ext_vector_type(8))) short bf16x8;
typedef __attribute__((ext_vector_type(4))) float f32x4;
typedef __attribute__((ext_vector_type(4))) unsigned short u16x4;

// ---------------------------------------------------------------------------
// Prep: pack [Wq;Wk;Wv] -> Wb192 bf16 [192][256] + bias192, and
//       Wout (o,c,ti,tj) -> W2b bf16 [o][t*64+c].
// ---------------------------------------------------------------------------
__global__ void prep_kernel(
    const float* __restrict__ Wq, const float* __restrict__ bq,
    const float* __restrict__ Wk, const float* __restrict__ bk,
    const float* __restrict__ Wv, const float* __restrict__ bv,
    const float* __restrict__ Wout,
    __hip_bfloat16* __restrict__ Wb192, float* __restrict__ bias192,
    __hip_bfloat16* __restrict__ W2b)
{
    const int idx = blockIdx.x * 256 + threadIdx.x;
    if (idx < 192 * 256) {
        const int row = idx >> 8, c = idx & 255;
        float wsrc;
        if (row < 64)       wsrc = Wq[row * 256 + c];
        else if (row < 128) wsrc = Wk[(row - 64) * 256 + c];
        else                wsrc = Wv[(row - 128) * 256 + c];
        Wb192[idx] = __float2bfloat16(wsrc);
        if (c == 0) {
            float bsrc;
            if (row < 64)       bsrc = bq[row];
            else if (row < 128) bsrc = bk[row - 64];
            else                bsrc = bv[row - 128];
            bias192[row] = bsrc;
        }
    } else if (idx < 192 * 256 + COUT * NTAP * COUT) {
        const int j = idx - 192 * 256;
        const int o = j / (NTAP * COUT);
        const int r = j - o * (NTAP * COUT);
        const int t = r >> 6;
        const int c = r & 63;
        W2b[j] = __float2bfloat16(Wout[((size_t)o * COUT + c) * NTAP + t]);
    }
}

// ---------------------------------------------------------------------------
// Kernel A (MFMA): QKV projection.  Writes v fp32 + qh (pre-scaled bf16) + kh.
// grid: B*HW/16 = 1024 blocks, 256 threads = 4 waves; wave owns 3 o-tiles.
// ---------------------------------------------------------------------------
__global__ __launch_bounds__(256) void qkv_mfma(
    const float* __restrict__ x,
    const __hip_bfloat16* __restrict__ Wb192, const float* __restrict__ bias192,
    float* __restrict__ v,
    __hip_bfloat16* __restrict__ qh, __hip_bfloat16* __restrict__ kh)
{
    const int blk = blockIdx.x;          // 0..1023
    const int b   = blk >> 8;
    const int p0  = (blk & 255) * 16;    // pixel within batch
    const int tid = threadIdx.x;
    const int wv  = tid >> 6;
    const int l   = tid & 63;
    const int lg  = l >> 4, lr = l & 15;

    __shared__ __attribute__((aligned(16))) __hip_bfloat16 xsh[16 * 256];

    // stage x[c][p0..p0+15] -> bf16 LDS transposed
    {
        const int c0 = tid >> 2;         // 0..63, +64/iter
        const int p4 = tid & 3;          // float4 index within row
        const float4* xb4 = (const float4*)(x + ((size_t)b * CIN) * HW + p0);
#pragma unroll
        for (int it = 0; it < 4; ++it) {
            const int cc = c0 + it * 64;
            const float4 xv = xb4[(size_t)cc * (HW / 4) + p4];
            __hip_bfloat16* dst = &xsh[((cc >> 3) * 16) * 8 + (cc & 7)];
            dst[(p4 * 4 + 0) * 8] = __float2bfloat16(xv.x);
            dst[(p4 * 4 + 1) * 8] = __float2bfloat16(xv.y);
            dst[(p4 * 4 + 2) * 8] = __float2bfloat16(xv.z);
            dst[(p4 * 4 + 3) * 8] = __float2bfloat16(xv.w);
        }
    }
    __syncthreads();

    f32x4 acc0 = {0.f,0.f,0.f,0.f}, acc1 = {0.f,0.f,0.f,0.f}, acc2 = {0.f,0.f,0.f,0.f};
    const short* wb  = (const short*)Wb192;
    const short* xs  = (const short*)xsh;

#pragma unroll
    for (int s = 0; s < 8; ++s) {
        const bf16x8 af = *(const bf16x8*)(xs + (size_t)(((s * 4 + lg) * 16 + lr)) * 8);
        const bf16x8 b0 = *(const bf16x8*)(wb + (size_t)((wv * 3 + 0) * 16 + lr) * 256 + s * 32 + lg * 8);
        const bf16x8 b1 = *(const bf16x8*)(wb + (size_t)((wv * 3 + 1) * 16 + lr) * 256 + s * 32 + lg * 8);
        const bf16x8 b2 = *(const bf16x8*)(wb + (size_t)((wv * 3 + 2) * 16 + lr) * 256 + s * 32 + lg * 8);
        acc0 = __builtin_amdgcn_mfma_f32_16x16x32_bf16(af, b0, acc0, 0, 0, 0);
        acc1 = __builtin_amdgcn_mfma_f32_16x16x32_bf16(af, b1, acc1, 0, 0, 0);
        acc2 = __builtin_amdgcn_mfma_f32_16x16x32_bf16(af, b2, acc2, 0, 0, 0);
    }

    // epilogue: row = pixel = p0 + lg*4 + j ; col = o = (otile&3)*16 + lr
    f32x4 accs[3] = {acc0, acc1, acc2};
#pragma unroll
    for (int i = 0; i < 3; ++i) {
        const int otile = wv * 3 + i;
        const int kind  = otile >> 2;            // 0=q 1=k 2=v
        const int o     = (otile & 3) * 16 + lr;
        const float bias = bias192[otile * 16 + lr];
#pragma unroll
        for (int j = 0; j < 4; ++j) {
            const int p = p0 + lg * 4 + j;
            const size_t addr = ((size_t)b * HW + p) * (size_t)COUT + o;
            const float val = accs[i][j] + bias;
            if (kind == 0)      { qh[addr] = __float2bfloat16(val * QSCALE); }
            else if (kind == 1) { kh[addr] = __float2bfloat16(val); }
            else                { v[addr] = val; }
        }
    }
}

// ---------------------------------------------------------------------------
// Kernel B (MFMA): per-row sum of exp(qk/8), diag forced to logit 0.
// grid: 4 b x 16 panels(256 rows) x 16 jsegs(256 cols) = 1024 blocks.
// Wave owns 64 Q-rows (4 row-tiles in registers); 1-deep K prefetch.
// ---------------------------------------------------------------------------
__global__ __launch_bounds__(256) void qk_stats_mfma(
    const __hip_bfloat16* __restrict__ qh, const __hip_bfloat16* __restrict__ kh,
    float* __restrict__ s_part)
{
    const int blk   = blockIdx.x;           // 0..1023
    const int b     = blk >> 8;             // 256 blocks per batch
    const int panel = (blk >> 4) & 15;      // 256-row panel
    const int jseg  = blk & 15;             // 256-col segment
    const int tid   = threadIdx.x;
    const int w     = tid >> 6;
    const int l     = tid & 63;
    const int lg    = l >> 4;
    const int lr    = l & 15;
    const int R0    = panel * 256 + w * 64; // wave's first Q row

    const short* qb = (const short*)(qh + ((size_t)b * HW) * COUT);
    const short* kb = (const short*)(kh + ((size_t)b * HW) * COUT);

    // A fragments: 4 row-tiles x 2 k-slices
    bf16x8 a[4][2];
#pragma unroll
    for (int rt = 0; rt < 4; ++rt) {
        a[rt][0] = *(const bf16x8*)(qb + (size_t)(R0 + rt * 16 + lr) * COUT + lg * 8);
        a[rt][1] = *(const bf16x8*)(qb + (size_t)(R0 + rt * 16 + lr) * COUT + 32 + lg * 8);
    }

    float s[4][4];
#pragma unroll
    for (int rt = 0; rt < 4; ++rt)
#pragma unroll
        for (int i = 0; i < 4; ++i) s[rt][i] = 0.f;

    const int j0 = jseg * 256;
    const short* kptr = kb + (size_t)(j0 + lr) * COUT + lg * 8;

    bf16x8 p0 = *(const bf16x8*)(kptr);
    bf16x8 p1 = *(const bf16x8*)(kptr + 32);
    kptr += 16 * COUT;

    for (int it = 0; it < 16; ++it) {
        bf16x8 n0, n1;
        if (it != 15) {
            n0 = *(const bf16x8*)(kptr);
            n1 = *(const bf16x8*)(kptr + 32);
            kptr += 16 * COUT;
        }
        const int jb = j0 + it * 16;
#pragma unroll
        for (int rt = 0; rt < 4; ++rt) {
            f32x4 d = {0.f, 0.f, 0.f, 0.f};
            d = __builtin_amdgcn_mfma_f32_16x16x32_bf16(a[rt][0], p0, d, 0, 0, 0);
            d = __builtin_amdgcn_mfma_f32_16x16x32_bf16(a[rt][1], p1, d, 0, 0, 0);
            if (jb == R0 + rt * 16) {
                d.x = (lr == lg * 4 + 0) ? 0.f : d.x;
                d.y = (lr == lg * 4 + 1) ? 0.f : d.y;
                d.z = (lr == lg * 4 + 2) ? 0.f : d.z;
                d.w = (lr == lg * 4 + 3) ? 0.f : d.w;
            }
            s[rt][0] += exp2f(d.x);
            s[rt][1] += exp2f(d.y);
            s[rt][2] += exp2f(d.z);
            s[rt][3] += exp2f(d.w);
        }
        p0 = n0; p1 = n1;
    }

    // reduce across the 16 lanes sharing a row-group, per row-tile
#pragma unroll
    for (int rt = 0; rt < 4; ++rt) {
#pragma unroll
        for (int off = 1; off < 16; off <<= 1) {
            s[rt][0] += __shfl_xor(s[rt][0], off, 64);
            s[rt][1] += __shfl_xor(s[rt][1], off, 64);
            s[rt][2] += __shfl_xor(s[rt][2], off, 64);
            s[rt][3] += __shfl_xor(s[rt][3], off, 64);
        }
        if (lr == 0) {
            float4 res = {s[rt][0], s[rt][1], s[rt][2], s[rt][3]};
            *(float4*)(s_part + (size_t)jseg * (BATCH * HW) + (size_t)b * HW +
                       R0 + rt * 16 + lg * 4) = res;
        }
    }
}

// ---------------------------------------------------------------------------
// Kernel C1 (MFMA): banded window attention weights.
// grid: B*HH*7 = 1792 blocks, 256 threads = 4 waves.
// ---------------------------------------------------------------------------
__global__ __launch_bounds__(256) void gcalc_mfma(
    const __hip_bfloat16* __restrict__ qh, const __hip_bfloat16* __restrict__ kh,
    const float* __restrict__ s_part, float* __restrict__ g)
{
    const int blk = blockIdx.x;            // ((b*64+h)*7 + dh)
    const int dh  = blk % 7;
    const int bh  = blk / 7;
    const int h   = bh & 63;
    const int b   = bh >> 6;
    const int tid = threadIdx.x;
    const int wv  = tid >> 6;
    const int l   = tid & 63;
    const int lg  = l >> 4, lr = l & 15;

    const int jh = min(max(h + dh - 3, 0), HH - 1);

    __shared__ float Dsh[64][65];
    __shared__ float rsh[64];

    // reciprocal row sums (denominator)
    if (tid < 64) {
        float s = 0.f;
        const size_t base = (size_t)b * HW + h * 64 + tid;
#pragma unroll
        for (int seg = 0; seg < NSEG; ++seg)
            s += s_part[(size_t)seg * (BATCH * HW) + base];
        rsh[tid] = 1.0f / s;
    }

    const short* qb = (const short*)(qh + ((size_t)b * HW + h * 64) * COUT);
    const short* kb = (const short*)(kh + ((size_t)b * HW + jh * 64) * COUT);

    const bf16x8 a0 = *(const bf16x8*)(qb + (size_t)(wv * 16 + lr) * COUT + lg * 8);
    const bf16x8 a1 = *(const bf16x8*)(qb + (size_t)(wv * 16 + lr) * COUT + 32 + lg * 8);

#pragma unroll
    for (int ct = 0; ct < 4; ++ct) {
        const bf16x8 b0 = *(const bf16x8*)(kb + (size_t)(ct * 16 + lr) * COUT + lg * 8);
        const bf16x8 b1 = *(const bf16x8*)(kb + (size_t)(ct * 16 + lr) * COUT + 32 + lg * 8);
        f32x4 d = {0.f, 0.f, 0.f, 0.f};
        d = __builtin_amdgcn_mfma_f32_16x16x32_bf16(a0, b0, d, 0, 0, 0);
        d = __builtin_amdgcn_mfma_f32_16x16x32_bf16(a1, b1, d, 0, 0, 0);
        const int row = wv * 16 + lg * 4;
        const int col = ct * 16 + lr;
        Dsh[row + 0][col] = d.x;
        Dsh[row + 1][col] = d.y;
        Dsh[row + 2][col] = d.z;
        Dsh[row + 3][col] = d.w;
    }
    __syncthreads();

    // band extraction: 64 w x 7 tj entries
    for (int e = tid; e < 64 * 7; e += 256) {
        const int w  = e / 7;
        const int tj = e - w * 7;
        const int jw = min(max(w + tj - 3, 0), WW - 1);
        const float num = (jh == h && jw == w) ? 1.0f : exp2f(Dsh[w][jw]);
        g[((size_t)b * HW + h * 64 + w) * NTAP + dh * 7 + tj] = num * rsh[w];
    }
}

// ---------------------------------------------------------------------------
// Kernel C2 (MFMA): out[b,p,o] = relu(bout[o] + sum_{t,c} gv[p][t*64+c]*W2[o][t*64+c])
// grid: B*HW/16 = 1024 blocks (4/CU), 256 threads = 4 waves; wave = o-tile.
// Per tap: stage gv[16 pixels][64 c] bf16 in LDS (coalesced v float4 loads,
// 1-deep register prefetch of the NEXT tap's v), double-buffered, ONE barrier
// per tap; 2 MFMA per wave per tap; fused bias/ReLU epilogue.
// ---------------------------------------------------------------------------
__global__ __launch_bounds__(256) void out_mfma(
    const float* __restrict__ g, const float* __restrict__ v,
    const __hip_bfloat16* __restrict__ W2b, const float* __restrict__ bout,
    float* __restrict__ out)
{
    const int blk = blockIdx.x;          // 0..1023
    const int b   = blk >> 8;
    const int p0  = (blk & 255) * 16;    // pixel within batch (same h row)
    const int h   = p0 >> 6;
    const int w0  = p0 & 63;             // 0,16,32,48
    const int tid = threadIdx.x;
    const int wv  = tid >> 6;            // o-tile
    const int l   = tid & 63;
    const int lg  = l >> 4, lr = l & 15;

    __shared__ __attribute__((aligned(16))) __hip_bfloat16 gvsh[2][16][72];
    __shared__ float gsh[16][NTAP];

    const int row0 = b * HW + p0;
    for (int i = tid; i < 16 * NTAP; i += 256) {
        const int w = i / NTAP, t = i - w * NTAP;
        gsh[w][t] = g[(size_t)(row0 + w) * NTAP + t];
    }

    // staging thread coords: pixel w (row within tile), float4 column fc4
    const int sw  = tid >> 4;            // 0..15
    const int fc4 = tid & 15;            // 0..15
    const float* vb = v + ((size_t)b * HW) * COUT;

    // v address for tap t (staging thread's float4)
    auto vptr = [&](int t) -> const float4* {
        const int dh = t / 7 - 3, dw = t - (t / 7) * 7 - 3;
        const int jh = min(max(h + dh, 0), HH - 1);
        const int jw = min(max(w0 + sw + dw, 0), WW - 1);
        return (const float4*)(vb + (size_t)((jh << 6) + jw) * COUT) + fc4;
    };

    float4 vv = *vptr(0);                // prefetch tap 0
    __syncthreads();                     // gsh ready

    f32x4 acc = {0.f, 0.f, 0.f, 0.f};
    const short* wrow = (const short*)W2b + (size_t)(wv * 16 + lr) * (NTAP * COUT);

    for (int t = 0; t < NTAP; ++t) {
        // stage gv for tap t from the prefetched registers
        const float gg = gsh[sw][t];
        u16x4 pk;
        pk.x = __builtin_bit_cast(unsigned short, __float2bfloat16(vv.x * gg));
        pk.y = __builtin_bit_cast(unsigned short, __float2bfloat16(vv.y * gg));
        pk.z = __builtin_bit_cast(unsigned short, __float2bfloat16(vv.z * gg));
        pk.w = __builtin_bit_cast(unsigned short, __float2bfloat16(vv.w * gg));
        *(u16x4*)(&gvsh[t & 1][sw][fc4 * 4]) = pk;

        // prefetch next tap's v while the barrier + MFMA run
        float4 vn;
        if (t != NTAP - 1) vn = *vptr(t + 1);

        // B fragments (global, L2-hot) — independent of LDS
        const bf16x8 B0 = *(const bf16x8*)(wrow + t * 64 + lg * 8);
        const bf16x8 B1 = *(const bf16x8*)(wrow + t * 64 + 32 + lg * 8);

        __syncthreads();
        const short* gsrc = (const short*)&gvsh[t & 1][0][0];
        const bf16x8 A0 = *(const bf16x8*)(gsrc + (size_t)lr * 72 + lg * 8);
        const bf16x8 A1 = *(const bf16x8*)(gsrc + (size_t)lr * 72 + 32 + lg * 8);
        acc = __builtin_amdgcn_mfma_f32_16x16x32_bf16(A0, B0, acc, 0, 0, 0);
        acc = __builtin_amdgcn_mfma_f32_16x16x32_bf16(A1, B1, acc, 0, 0, 0);

        vv = vn;
    }

    // epilogue: D[row=lg*4+j][col=lr] -> pixel p0+lg*4+j, o = wv*16+lr
    const int o  = wv * 16 + lr;
    const float bo = bout[o];
    float4 r;
    r.x = fmaxf(acc.x + bo, 0.f);
    r.y = fmaxf(acc.y + bo, 0.f);
    r.z = fmaxf(acc.z + bo, 0.f);
    r.w = fmaxf(acc.w + bo, 0.f);
    *(float4*)(out + ((size_t)(b * COUT + o) * HW) + p0 + lg * 4) = r;
}

// ---------------------------------------------------------------------------
extern "C" void kernel_launch(void* const* d_in, const int* in_sizes, int n_in,
                              void* d_out, int out_size, void* d_ws, size_t ws_size,
                              hipStream_t stream)
{
    const float* x    = (const float*)d_in[0];
    const float* Wq   = (const float*)d_in[1];
    const float* bq   = (const float*)d_in[2];
    const float* Wk   = (const float*)d_in[3];
    const float* bk   = (const float*)d_in[4];
    const float* Wv   = (const float*)d_in[5];
    const float* bv   = (const float*)d_in[6];
    const float* Wout = (const float*)d_in[7];
    const float* bout = (const float*)d_in[8];
    float* out = (float*)d_out;

    // workspace layout (float units)
    float* ws      = (float*)d_ws;
    float* v       = ws;                                 // 1,048,576
    float* s_part  = v + (size_t)BATCH * HW * COUT;      // NSEG * B*HW
    float* g       = s_part + (size_t)NSEG * BATCH * HW; // 802,816
    float* bias192 = g + (size_t)BATCH * HW * NTAP;      // 192 (+pad)
    __hip_bfloat16* qh    = (__hip_bfloat16*)(bias192 + 256);
    __hip_bfloat16* kh    = qh + (size_t)BATCH * HW * COUT;
    __hip_bfloat16* W2b   = kh + (size_t)BATCH * HW * COUT;   // 200,704 bf16
    __hip_bfloat16* Wb192 = W2b + (size_t)COUT * NTAP * COUT; // 49,152 bf16

    prep_kernel<<<(192 * 256 + COUT * NTAP * COUT + 255) / 256, 256, 0, stream>>>(
        Wq, bq, Wk, bk, Wv, bv, Wout, Wb192, bias192, W2b);
    qkv_mfma<<<BATCH * (HW / 16), 256, 0, stream>>>(x, Wb192, bias192, v, qh, kh);
    qk_stats_mfma<<<BATCH * 16 * NSEG, 256, 0, stream>>>(qh, kh, s_part);
    gcalc_mfma<<<BATCH * HH * 7, 256, 0, stream>>>(qh, kh, s_part, g);
    out_mfma<<<BATCH * (HW / 16), 256, 0, stream>>>(g, v, W2b, bout, out);
}

// Round 11
// 194.038 us; speedup vs baseline: 1.0188x; 1.0188x over previous
//
#include <hip/hip_runtime.h>
#include <hip/hip_bf16.h>
#include <math.h>

// Problem constants
#define BATCH 4
#define CIN   256
#define HH    64
#define WW    64
#define HW    4096      // HH*WW
#define COUT  64
#define KK    7
#define NTAP  49
#define NSEG  16        // j-segments in qk_stats (256 cols each)

// exp(d/8) == exp2(d * (log2e/8)); fold scale into bf16 q
#define QSCALE 0.18033688011112042f

typedef __attribute__((ext_vector_type(8))) short bf16x8;
typedef __attribute__((ext_vector_type(4))) float f32x4;

// ---------------------------------------------------------------------------
// Prep: pack [Wq;Wk;Wv] -> Wb192 bf16 [192][256] + bias192, and
//       Wout (o,c,ti,tj) -> W2b bf16 [o][t*64+c].
// ---------------------------------------------------------------------------
__global__ void prep_kernel(
    const float* __restrict__ Wq, const float* __restrict__ bq,
    const float* __restrict__ Wk, const float* __restrict__ bk,
    const float* __restrict__ Wv, const float* __restrict__ bv,
    const float* __restrict__ Wout,
    __hip_bfloat16* __restrict__ Wb192, float* __restrict__ bias192,
    __hip_bfloat16* __restrict__ W2b)
{
    const int idx = blockIdx.x * 256 + threadIdx.x;
    if (idx < 192 * 256) {
        const int row = idx >> 8, c = idx & 255;
        float wsrc;
        if (row < 64)       wsrc = Wq[row * 256 + c];
        else if (row < 128) wsrc = Wk[(row - 64) * 256 + c];
        else                wsrc = Wv[(row - 128) * 256 + c];
        Wb192[idx] = __float2bfloat16(wsrc);
        if (c == 0) {
            float bsrc;
            if (row < 64)       bsrc = bq[row];
            else if (row < 128) bsrc = bk[row - 64];
            else                bsrc = bv[row - 128];
            bias192[row] = bsrc;
        }
    } else if (idx < 192 * 256 + COUT * NTAP * COUT) {
        const int j = idx - 192 * 256;
        const int o = j / (NTAP * COUT);
        const int r = j - o * (NTAP * COUT);
        const int t = r >> 6;
        const int c = r & 63;
        W2b[j] = __float2bfloat16(Wout[((size_t)o * COUT + c) * NTAP + t]);
    }
}

// ---------------------------------------------------------------------------
// Kernel A (MFMA): QKV projection.  Writes qh (pre-scaled bf16), kh, vh bf16.
// grid: B*HW/16 = 1024 blocks, 256 threads = 4 waves; wave owns 3 o-tiles.
// ---------------------------------------------------------------------------
__global__ __launch_bounds__(256) void qkv_mfma(
    const float* __restrict__ x,
    const __hip_bfloat16* __restrict__ Wb192, const float* __restrict__ bias192,
    __hip_bfloat16* __restrict__ qh, __hip_bfloat16* __restrict__ kh,
    __hip_bfloat16* __restrict__ vh)
{
    const int blk = blockIdx.x;          // 0..1023
    const int b   = blk >> 8;
    const int p0  = (blk & 255) * 16;    // pixel within batch
    const int tid = threadIdx.x;
    const int wv  = tid >> 6;
    const int l   = tid & 63;
    const int lg  = l >> 4, lr = l & 15;

    __shared__ __attribute__((aligned(16))) __hip_bfloat16 xsh[16 * 256];

    // stage x[c][p0..p0+15] -> bf16 LDS transposed
    {
        const int c0 = tid >> 2;         // 0..63, +64/iter
        const int p4 = tid & 3;          // float4 index within row
        const float4* xb4 = (const float4*)(x + ((size_t)b * CIN) * HW + p0);
#pragma unroll
        for (int it = 0; it < 4; ++it) {
            const int cc = c0 + it * 64;
            const float4 xv = xb4[(size_t)cc * (HW / 4) + p4];
            __hip_bfloat16* dst = &xsh[((cc >> 3) * 16) * 8 + (cc & 7)];
            dst[(p4 * 4 + 0) * 8] = __float2bfloat16(xv.x);
            dst[(p4 * 4 + 1) * 8] = __float2bfloat16(xv.y);
            dst[(p4 * 4 + 2) * 8] = __float2bfloat16(xv.z);
            dst[(p4 * 4 + 3) * 8] = __float2bfloat16(xv.w);
        }
    }
    __syncthreads();

    f32x4 acc0 = {0.f,0.f,0.f,0.f}, acc1 = {0.f,0.f,0.f,0.f}, acc2 = {0.f,0.f,0.f,0.f};
    const short* wb  = (const short*)Wb192;
    const short* xs  = (const short*)xsh;

#pragma unroll
    for (int s = 0; s < 8; ++s) {
        const bf16x8 af = *(const bf16x8*)(xs + (size_t)(((s * 4 + lg) * 16 + lr)) * 8);
        const bf16x8 b0 = *(const bf16x8*)(wb + (size_t)((wv * 3 + 0) * 16 + lr) * 256 + s * 32 + lg * 8);
        const bf16x8 b1 = *(const bf16x8*)(wb + (size_t)((wv * 3 + 1) * 16 + lr) * 256 + s * 32 + lg * 8);
        const bf16x8 b2 = *(const bf16x8*)(wb + (size_t)((wv * 3 + 2) * 16 + lr) * 256 + s * 32 + lg * 8);
        acc0 = __builtin_amdgcn_mfma_f32_16x16x32_bf16(af, b0, acc0, 0, 0, 0);
        acc1 = __builtin_amdgcn_mfma_f32_16x16x32_bf16(af, b1, acc1, 0, 0, 0);
        acc2 = __builtin_amdgcn_mfma_f32_16x16x32_bf16(af, b2, acc2, 0, 0, 0);
    }

    // epilogue: row = pixel = p0 + lg*4 + j ; col = o = (otile&3)*16 + lr
    f32x4 accs[3] = {acc0, acc1, acc2};
#pragma unroll
    for (int i = 0; i < 3; ++i) {
        const int otile = wv * 3 + i;
        const int kind  = otile >> 2;            // 0=q 1=k 2=v
        const int o     = (otile & 3) * 16 + lr;
        const float bias = bias192[otile * 16 + lr];
#pragma unroll
        for (int j = 0; j < 4; ++j) {
            const int p = p0 + lg * 4 + j;
            const size_t addr = ((size_t)b * HW + p) * (size_t)COUT + o;
            const float val = accs[i][j] + bias;
            if (kind == 0)      { qh[addr] = __float2bfloat16(val * QSCALE); }
            else if (kind == 1) { kh[addr] = __float2bfloat16(val); }
            else                { vh[addr] = __float2bfloat16(val); }
        }
    }
}

// ---------------------------------------------------------------------------
// Kernel B (MFMA): per-row sum of exp(qk/8), diag forced to logit 0.
// grid: 4 b x 16 panels(256 rows) x 16 jsegs(256 cols) = 1024 blocks.
// ---------------------------------------------------------------------------
__global__ __launch_bounds__(256) void qk_stats_mfma(
    const __hip_bfloat16* __restrict__ qh, const __hip_bfloat16* __restrict__ kh,
    float* __restrict__ s_part)
{
    const int blk   = blockIdx.x;           // 0..1023
    const int b     = blk >> 8;             // 256 blocks per batch
    const int panel = (blk >> 4) & 15;      // 256-row panel
    const int jseg  = blk & 15;             // 256-col segment
    const int tid   = threadIdx.x;
    const int w     = tid >> 6;
    const int l     = tid & 63;
    const int lg    = l >> 4;
    const int lr    = l & 15;
    const int R0    = panel * 256 + w * 64; // wave's first Q row

    const short* qb = (const short*)(qh + ((size_t)b * HW) * COUT);
    const short* kb = (const short*)(kh + ((size_t)b * HW) * COUT);

    bf16x8 a[4][2];
#pragma unroll
    for (int rt = 0; rt < 4; ++rt) {
        a[rt][0] = *(const bf16x8*)(qb + (size_t)(R0 + rt * 16 + lr) * COUT + lg * 8);
        a[rt][1] = *(const bf16x8*)(qb + (size_t)(R0 + rt * 16 + lr) * COUT + 32 + lg * 8);
    }

    float s[4][4];
#pragma unroll
    for (int rt = 0; rt < 4; ++rt)
#pragma unroll
        for (int i = 0; i < 4; ++i) s[rt][i] = 0.f;

    const int j0 = jseg * 256;
    const short* kptr = kb + (size_t)(j0 + lr) * COUT + lg * 8;

    bf16x8 p0 = *(const bf16x8*)(kptr);
    bf16x8 p1 = *(const bf16x8*)(kptr + 32);
    kptr += 16 * COUT;

    for (int it = 0; it < 16; ++it) {
        bf16x8 n0, n1;
        if (it != 15) {
            n0 = *(const bf16x8*)(kptr);
            n1 = *(const bf16x8*)(kptr + 32);
            kptr += 16 * COUT;
        }
        const int jb = j0 + it * 16;
#pragma unroll
        for (int rt = 0; rt < 4; ++rt) {
            f32x4 d = {0.f, 0.f, 0.f, 0.f};
            d = __builtin_amdgcn_mfma_f32_16x16x32_bf16(a[rt][0], p0, d, 0, 0, 0);
            d = __builtin_amdgcn_mfma_f32_16x16x32_bf16(a[rt][1], p1, d, 0, 0, 0);
            if (jb == R0 + rt * 16) {
                d.x = (lr == lg * 4 + 0) ? 0.f : d.x;
                d.y = (lr == lg * 4 + 1) ? 0.f : d.y;
                d.z = (lr == lg * 4 + 2) ? 0.f : d.z;
                d.w = (lr == lg * 4 + 3) ? 0.f : d.w;
            }
            s[rt][0] += exp2f(d.x);
            s[rt][1] += exp2f(d.y);
            s[rt][2] += exp2f(d.z);
            s[rt][3] += exp2f(d.w);
        }
        p0 = n0; p1 = n1;
    }

#pragma unroll
    for (int rt = 0; rt < 4; ++rt) {
#pragma unroll
        for (int off = 1; off < 16; off <<= 1) {
            s[rt][0] += __shfl_xor(s[rt][0], off, 64);
            s[rt][1] += __shfl_xor(s[rt][1], off, 64);
            s[rt][2] += __shfl_xor(s[rt][2], off, 64);
            s[rt][3] += __shfl_xor(s[rt][3], off, 64);
        }
        if (lr == 0) {
            float4 res = {s[rt][0], s[rt][1], s[rt][2], s[rt][3]};
            *(float4*)(s_part + (size_t)jseg * (BATCH * HW) + (size_t)b * HW +
                       R0 + rt * 16 + lg * 4) = res;
        }
    }
}

// ---------------------------------------------------------------------------
// Kernel C1 (MFMA): banded window attention weights.
// grid: B*HH*7 = 1792 blocks, 256 threads = 4 waves.
// ---------------------------------------------------------------------------
__global__ __launch_bounds__(256) void gcalc_mfma(
    const __hip_bfloat16* __restrict__ qh, const __hip_bfloat16* __restrict__ kh,
    const float* __restrict__ s_part, float* __restrict__ g)
{
    const int blk = blockIdx.x;            // ((b*64+h)*7 + dh)
    const int dh  = blk % 7;
    const int bh  = blk / 7;
    const int h   = bh & 63;
    const int b   = bh >> 6;
    const int tid = threadIdx.x;
    const int wv  = tid >> 6;
    const int l   = tid & 63;
    const int lg  = l >> 4, lr = l & 15;

    const int jh = min(max(h + dh - 3, 0), HH - 1);

    __shared__ float Dsh[64][65];
    __shared__ float rsh[64];

    if (tid < 64) {
        float s = 0.f;
        const size_t base = (size_t)b * HW + h * 64 + tid;
#pragma unroll
        for (int seg = 0; seg < NSEG; ++seg)
            s += s_part[(size_t)seg * (BATCH * HW) + base];
        rsh[tid] = 1.0f / s;
    }

    const short* qb = (const short*)(qh + ((size_t)b * HW + h * 64) * COUT);
    const short* kb = (const short*)(kh + ((size_t)b * HW + jh * 64) * COUT);

    const bf16x8 a0 = *(const bf16x8*)(qb + (size_t)(wv * 16 + lr) * COUT + lg * 8);
    const bf16x8 a1 = *(const bf16x8*)(qb + (size_t)(wv * 16 + lr) * COUT + 32 + lg * 8);

#pragma unroll
    for (int ct = 0; ct < 4; ++ct) {
        const bf16x8 b0 = *(const bf16x8*)(kb + (size_t)(ct * 16 + lr) * COUT + lg * 8);
        const bf16x8 b1 = *(const bf16x8*)(kb + (size_t)(ct * 16 + lr) * COUT + 32 + lg * 8);
        f32x4 d = {0.f, 0.f, 0.f, 0.f};
        d = __builtin_amdgcn_mfma_f32_16x16x32_bf16(a0, b0, d, 0, 0, 0);
        d = __builtin_amdgcn_mfma_f32_16x16x32_bf16(a1, b1, d, 0, 0, 0);
        const int row = wv * 16 + lg * 4;
        const int col = ct * 16 + lr;
        Dsh[row + 0][col] = d.x;
        Dsh[row + 1][col] = d.y;
        Dsh[row + 2][col] = d.z;
        Dsh[row + 3][col] = d.w;
    }
    __syncthreads();

    for (int e = tid; e < 64 * 7; e += 256) {
        const int w  = e / 7;
        const int tj = e - w * 7;
        const int jw = min(max(w + tj - 3, 0), WW - 1);
        const float num = (jh == h && jw == w) ? 1.0f : exp2f(Dsh[w][jw]);
        g[((size_t)b * HW + h * 64 + w) * NTAP + dh * 7 + tj] = num * rsh[w];
    }
}

// ---------------------------------------------------------------------------
// Kernel C2 (MFMA): out[p,o] = relu(bout[o] + sum_t g[p,t] * (v[nb(p,t)] . W2_t[o]))
// g folded AFTER the MFMA (register FMA on the D tile) -> V staged ONCE.
// grid: B*HH = 256 blocks (1/CU), 256 threads = 4 waves; wave = 16-pixel
// row-tile rt, computes all 4 o-tiles.  V window [7dh][8s][64w] bf16 in LDS,
// plane stride 65 units (16B) -> conflict-free ds_read_b128.  g transposed
// [t][p] so the 4 per-row factors are one broadcast b128.  No barriers in
// the 49-tap loop; 1-deep register prefetch of A/B/g.
// ---------------------------------------------------------------------------
__global__ __launch_bounds__(256) void out_mfma(
    const float* __restrict__ g, const __hip_bfloat16* __restrict__ vh,
    const __hip_bfloat16* __restrict__ W2b, const float* __restrict__ bout,
    float* __restrict__ out)
{
    const int blk = blockIdx.x;          // b*64 + h
    const int b   = blk >> 6;
    const int h   = blk & 63;
    const int tid = threadIdx.x;
    const int rt  = tid >> 6;            // wave = row-tile (16 pixels)
    const int l   = tid & 63;
    const int lg  = l >> 4, lr = l & 15;

    // vsh unit (dh,s,w) at (dh*8+s)*65 + w ; unit = 8 bf16 = 16B
    __shared__ __attribute__((aligned(16))) __hip_bfloat16 vsh[3640 * 8];
    __shared__ __attribute__((aligned(16))) float gshT[NTAP * 68];
    __shared__ __attribute__((aligned(16))) float osh[64 * 68];

    // ---- stage V window: 7 rows x 64 w x 8 slices (coalesced, one shot)
    {
        const short* vhs = (const short*)vh + (size_t)b * HW * COUT;
#pragma unroll
        for (int k = 0; k < 14; ++k) {
            const int idx = k * 256 + tid;       // 0..3583
            const int s  = idx & 7;
            const int w  = (idx >> 3) & 63;
            const int dh = idx >> 9;
            const int jh = min(max(h + dh - 3, 0), HH - 1);
            const bf16x8 val = *(const bf16x8*)(vhs + ((size_t)(jh * 64 + w)) * COUT + s * 8);
            *(bf16x8*)((short*)vsh + (size_t)((dh * 8 + s) * 65 + w) * 8) = val;
        }
    }
    // ---- stage g transposed: gshT[t*68 + p]
    {
        const float* grow = g + (size_t)(b * HW + h * 64) * NTAP;
#pragma unroll
        for (int k = 0; k < 13; ++k) {
            const int idx = k * 256 + tid;
            if (idx < 64 * NTAP) {
                const int p = idx / NTAP, t = idx - p * NTAP;
                gshT[t * 68 + p] = grow[idx];
            }
        }
    }
    __syncthreads();

    f32x4 acc[4];
#pragma unroll
    for (int ot = 0; ot < 4; ++ot) acc[ot] = (f32x4){0.f, 0.f, 0.f, 0.f};

    const short* vs  = (const short*)vsh;
    const short* wb2 = (const short*)W2b;
    const int px = rt * 16 + lr;         // lane's pixel (column in row)

    // prefetch tap 0 (dh=0, dw=-3)
    bf16x8 Ac0, Ac1, Bc[4][2];
    f32x4 gc;
    {
        const int wc = min(max(px - 3, 0), 63);
        Ac0 = *(const bf16x8*)(vs + (size_t)((0 + lg) * 65 + wc) * 8);
        Ac1 = *(const bf16x8*)(vs + (size_t)((4 + lg) * 65 + wc) * 8);
#pragma unroll
        for (int ot = 0; ot < 4; ++ot) {
            const size_t wr = (size_t)(ot * 16 + lr) * (NTAP * COUT);
            Bc[ot][0] = *(const bf16x8*)(wb2 + wr + lg * 8);
            Bc[ot][1] = *(const bf16x8*)(wb2 + wr + 32 + lg * 8);
        }
        gc = *(const f32x4*)(gshT + rt * 16 + lg * 4);
    }

    for (int t = 0; t < NTAP; ++t) {
        bf16x8 An0, An1, Bn[4][2];
        f32x4 gn;
        if (t + 1 < NTAP) {
            const int tn = t + 1;
            const int dh = tn / 7, dw = tn - dh * 7 - 3;
            const int wc = min(max(px + dw, 0), 63);
            An0 = *(const bf16x8*)(vs + (size_t)((dh * 8 + lg) * 65 + wc) * 8);
            An1 = *(const bf16x8*)(vs + (size_t)((dh * 8 + 4 + lg) * 65 + wc) * 8);
#pragma unroll
            for (int ot = 0; ot < 4; ++ot) {
                const size_t wr = (size_t)(ot * 16 + lr) * (NTAP * COUT) + tn * 64;
                Bn[ot][0] = *(const bf16x8*)(wb2 + wr + lg * 8);
                Bn[ot][1] = *(const bf16x8*)(wb2 + wr + 32 + lg * 8);
            }
            gn = *(const f32x4*)(gshT + tn * 68 + rt * 16 + lg * 4);
        }

#pragma unroll
        for (int ot = 0; ot < 4; ++ot) {
            f32x4 d = {0.f, 0.f, 0.f, 0.f};
            d = __builtin_amdgcn_mfma_f32_16x16x32_bf16(Ac0, Bc[ot][0], d, 0, 0, 0);
            d = __builtin_amdgcn_mfma_f32_16x16x32_bf16(Ac1, Bc[ot][1], d, 0, 0, 0);
            acc[ot] += gc * d;           // D row = pixel rt*16+lg*4+j
        }

        Ac0 = An0; Ac1 = An1; gc = gn;
#pragma unroll
        for (int ot = 0; ot < 4; ++ot) { Bc[ot][0] = Bn[ot][0]; Bc[ot][1] = Bn[ot][1]; }
    }

    // transpose via LDS for coalesced stores: osh[o][pixel]
#pragma unroll
    for (int ot = 0; ot < 4; ++ot)
        *(f32x4*)(osh + (size_t)(ot * 16 + lr) * 68 + rt * 16 + lg * 4) = acc[ot];
    __syncthreads();

    const int o  = tid >> 2;
    const int c4 = tid & 3;
    const float bo = bout[o];
    float* obase = out + ((size_t)(b * COUT + o)) * HW + h * 64;
#pragma unroll
    for (int i = 0; i < 4; ++i) {
        const int p = c4 * 16 + i * 4;
        float4 vo = *(const float4*)(osh + (size_t)o * 68 + p);
        vo.x = fmaxf(vo.x + bo, 0.f);
        vo.y = fmaxf(vo.y + bo, 0.f);
        vo.z = fmaxf(vo.z + bo, 0.f);
        vo.w = fmaxf(vo.w + bo, 0.f);
        *(float4*)(obase + p) = vo;
    }
}

// ---------------------------------------------------------------------------
extern "C" void kernel_launch(void* const* d_in, const int* in_sizes, int n_in,
                              void* d_out, int out_size, void* d_ws, size_t ws_size,
                              hipStream_t stream)
{
    const float* x    = (const float*)d_in[0];
    const float* Wq   = (const float*)d_in[1];
    const float* bq   = (const float*)d_in[2];
    const float* Wk   = (const float*)d_in[3];
    const float* bk   = (const float*)d_in[4];
    const float* Wv   = (const float*)d_in[5];
    const float* bv   = (const float*)d_in[6];
    const float* Wout = (const float*)d_in[7];
    const float* bout = (const float*)d_in[8];
    float* out = (float*)d_out;

    // workspace layout (float units)
    float* ws      = (float*)d_ws;
    float* s_part  = ws;                                  // NSEG * B*HW
    float* g       = s_part + (size_t)NSEG * BATCH * HW;  // 802,816
    float* bias192 = g + (size_t)BATCH * HW * NTAP;       // 192 (+pad)
    __hip_bfloat16* qh    = (__hip_bfloat16*)(bias192 + 256);
    __hip_bfloat16* kh    = qh + (size_t)BATCH * HW * COUT;
    __hip_bfloat16* vh    = kh + (size_t)BATCH * HW * COUT;
    __hip_bfloat16* W2b   = vh + (size_t)BATCH * HW * COUT;   // 200,704 bf16
    __hip_bfloat16* Wb192 = W2b + (size_t)COUT * NTAP * COUT; // 49,152 bf16

    prep_kernel<<<(192 * 256 + COUT * NTAP * COUT + 255) / 256, 256, 0, stream>>>(
        Wq, bq, Wk, bk, Wv, bv, Wout, Wb192, bias192, W2b);
    qkv_mfma<<<BATCH * (HW / 16), 256, 0, stream>>>(x, Wb192, bias192, qh, kh, vh);
    qk_stats_mfma<<<BATCH * 16 * NSEG, 256, 0, stream>>>(qh, kh, s_part);
    gcalc_mfma<<<BATCH * HH * 7, 256, 0, stream>>>(qh, kh, s_part, g);
    out_mfma<<<BATCH * HH, 256, 0, stream>>>(g, vh, W2b, bout, out);
}

// Round 12
// 168.591 us; speedup vs baseline: 1.1726x; 1.1509x over previous
//
#include <hip/hip_runtime.h>
#include <hip/hip_bf16.h>
#include <math.h>

// Problem constants
#define BATCH 4
#define CIN   256
#define HH    64
#define WW    64
#define HW    4096      // HH*WW
#define COUT  64
#define KK    7
#define NTAP  49
#define NSEG  16        // j-segments in qk_stats (256 cols each)

// exp(d/8) == exp2(d * (log2e/8)); fold scale into bf16 q
#define QSCALE 0.18033688011112042f

typedef __attribute__((ext_vector_type(8))) short bf16x8;
typedef __attribute__((ext_vector_type(4))) float f32x4;
typedef __attribute__((ext_vector_type(4))) unsigned short u16x4;

// ---------------------------------------------------------------------------
// Prep: pack [Wq;Wk;Wv] -> Wb192 bf16 [192][256] + bias192, and
//       Wout (o,c,ti,tj) -> W2p bf16 [t][kblk(8)][o(64)][8]  (B-coalesced).
// ---------------------------------------------------------------------------
__global__ void prep_kernel(
    const float* __restrict__ Wq, const float* __restrict__ bq,
    const float* __restrict__ Wk, const float* __restrict__ bk,
    const float* __restrict__ Wv, const float* __restrict__ bv,
    const float* __restrict__ Wout,
    __hip_bfloat16* __restrict__ Wb192, float* __restrict__ bias192,
    __hip_bfloat16* __restrict__ W2p)
{
    const int idx = blockIdx.x * 256 + threadIdx.x;
    if (idx < 192 * 256) {
        const int row = idx >> 8, c = idx & 255;
        float wsrc;
        if (row < 64)       wsrc = Wq[row * 256 + c];
        else if (row < 128) wsrc = Wk[(row - 64) * 256 + c];
        else                wsrc = Wv[(row - 128) * 256 + c];
        Wb192[idx] = __float2bfloat16(wsrc);
        if (c == 0) {
            float bsrc;
            if (row < 64)       bsrc = bq[row];
            else if (row < 128) bsrc = bk[row - 64];
            else                bsrc = bv[row - 128];
            bias192[row] = bsrc;
        }
    } else if (idx < 192 * 256 + NTAP * 8 * COUT * 8) {
        const int j  = idx - 192 * 256;
        const int e  = j & 7;
        const int o  = (j >> 3) & 63;
        const int kb = (j >> 9) & 7;
        const int t  = j >> 12;
        const int c  = kb * 8 + e;
        W2p[j] = __float2bfloat16(Wout[((size_t)o * COUT + c) * NTAP + t]);
    }
}

// ---------------------------------------------------------------------------
// Kernel A (MFMA): QKV projection.  Writes v fp32 + qh (pre-scaled bf16) + kh.
// grid: B*HW/16 = 1024 blocks, 256 threads = 4 waves; wave owns 3 o-tiles.
// ---------------------------------------------------------------------------
__global__ __launch_bounds__(256) void qkv_mfma(
    const float* __restrict__ x,
    const __hip_bfloat16* __restrict__ Wb192, const float* __restrict__ bias192,
    float* __restrict__ v,
    __hip_bfloat16* __restrict__ qh, __hip_bfloat16* __restrict__ kh)
{
    const int blk = blockIdx.x;          // 0..1023
    const int b   = blk >> 8;
    const int p0  = (blk & 255) * 16;    // pixel within batch
    const int tid = threadIdx.x;
    const int wv  = tid >> 6;
    const int l   = tid & 63;
    const int lg  = l >> 4, lr = l & 15;

    __shared__ __attribute__((aligned(16))) __hip_bfloat16 xsh[16 * 256];

    // stage x[c][p0..p0+15] -> bf16 LDS transposed
    {
        const int c0 = tid >> 2;         // 0..63, +64/iter
        const int p4 = tid & 3;          // float4 index within row
        const float4* xb4 = (const float4*)(x + ((size_t)b * CIN) * HW + p0);
#pragma unroll
        for (int it = 0; it < 4; ++it) {
            const int cc = c0 + it * 64;
            const float4 xv = xb4[(size_t)cc * (HW / 4) + p4];
            __hip_bfloat16* dst = &xsh[((cc >> 3) * 16) * 8 + (cc & 7)];
            dst[(p4 * 4 + 0) * 8] = __float2bfloat16(xv.x);
            dst[(p4 * 4 + 1) * 8] = __float2bfloat16(xv.y);
            dst[(p4 * 4 + 2) * 8] = __float2bfloat16(xv.z);
            dst[(p4 * 4 + 3) * 8] = __float2bfloat16(xv.w);
        }
    }
    __syncthreads();

    f32x4 acc0 = {0.f,0.f,0.f,0.f}, acc1 = {0.f,0.f,0.f,0.f}, acc2 = {0.f,0.f,0.f,0.f};
    const short* wb  = (const short*)Wb192;
    const short* xs  = (const short*)xsh;

#pragma unroll
    for (int s = 0; s < 8; ++s) {
        const bf16x8 af = *(const bf16x8*)(xs + (size_t)(((s * 4 + lg) * 16 + lr)) * 8);
        const bf16x8 b0 = *(const bf16x8*)(wb + (size_t)((wv * 3 + 0) * 16 + lr) * 256 + s * 32 + lg * 8);
        const bf16x8 b1 = *(const bf16x8*)(wb + (size_t)((wv * 3 + 1) * 16 + lr) * 256 + s * 32 + lg * 8);
        const bf16x8 b2 = *(const bf16x8*)(wb + (size_t)((wv * 3 + 2) * 16 + lr) * 256 + s * 32 + lg * 8);
        acc0 = __builtin_amdgcn_mfma_f32_16x16x32_bf16(af, b0, acc0, 0, 0, 0);
        acc1 = __builtin_amdgcn_mfma_f32_16x16x32_bf16(af, b1, acc1, 0, 0, 0);
        acc2 = __builtin_amdgcn_mfma_f32_16x16x32_bf16(af, b2, acc2, 0, 0, 0);
    }

    // epilogue: row = pixel = p0 + lg*4 + j ; col = o = (otile&3)*16 + lr
    f32x4 accs[3] = {acc0, acc1, acc2};
#pragma unroll
    for (int i = 0; i < 3; ++i) {
        const int otile = wv * 3 + i;
        const int kind  = otile >> 2;            // 0=q 1=k 2=v
        const int o     = (otile & 3) * 16 + lr;
        const float bias = bias192[otile * 16 + lr];
#pragma unroll
        for (int j = 0; j < 4; ++j) {
            const int p = p0 + lg * 4 + j;
            const size_t addr = ((size_t)b * HW + p) * (size_t)COUT + o;
            const float val = accs[i][j] + bias;
            if (kind == 0)      { qh[addr] = __float2bfloat16(val * QSCALE); }
            else if (kind == 1) { kh[addr] = __float2bfloat16(val); }
            else                { v[addr] = val; }
        }
    }
}

// ---------------------------------------------------------------------------
// Kernel B (MFMA): per-row sum of exp(qk/8), diag forced to logit 0.
// grid: 4 b x 16 panels(256 rows) x 16 jsegs(256 cols) = 1024 blocks.
// ---------------------------------------------------------------------------
__global__ __launch_bounds__(256) void qk_stats_mfma(
    const __hip_bfloat16* __restrict__ qh, const __hip_bfloat16* __restrict__ kh,
    float* __restrict__ s_part)
{
    const int blk   = blockIdx.x;           // 0..1023
    const int b     = blk >> 8;             // 256 blocks per batch
    const int panel = (blk >> 4) & 15;      // 256-row panel
    const int jseg  = blk & 15;             // 256-col segment
    const int tid   = threadIdx.x;
    const int w     = tid >> 6;
    const int l     = tid & 63;
    const int lg    = l >> 4;
    const int lr    = l & 15;
    const int R0    = panel * 256 + w * 64; // wave's first Q row

    const short* qb = (const short*)(qh + ((size_t)b * HW) * COUT);
    const short* kb = (const short*)(kh + ((size_t)b * HW) * COUT);

    bf16x8 a[4][2];
#pragma unroll
    for (int rt = 0; rt < 4; ++rt) {
        a[rt][0] = *(const bf16x8*)(qb + (size_t)(R0 + rt * 16 + lr) * COUT + lg * 8);
        a[rt][1] = *(const bf16x8*)(qb + (size_t)(R0 + rt * 16 + lr) * COUT + 32 + lg * 8);
    }

    float s[4][4];
#pragma unroll
    for (int rt = 0; rt < 4; ++rt)
#pragma unroll
        for (int i = 0; i < 4; ++i) s[rt][i] = 0.f;

    const int j0 = jseg * 256;
    const short* kptr = kb + (size_t)(j0 + lr) * COUT + lg * 8;

    bf16x8 p0 = *(const bf16x8*)(kptr);
    bf16x8 p1 = *(const bf16x8*)(kptr + 32);
    kptr += 16 * COUT;

    for (int it = 0; it < 16; ++it) {
        bf16x8 n0, n1;
        if (it != 15) {
            n0 = *(const bf16x8*)(kptr);
            n1 = *(const bf16x8*)(kptr + 32);
            kptr += 16 * COUT;
        }
        const int jb = j0 + it * 16;
#pragma unroll
        for (int rt = 0; rt < 4; ++rt) {
            f32x4 d = {0.f, 0.f, 0.f, 0.f};
            d = __builtin_amdgcn_mfma_f32_16x16x32_bf16(a[rt][0], p0, d, 0, 0, 0);
            d = __builtin_amdgcn_mfma_f32_16x16x32_bf16(a[rt][1], p1, d, 0, 0, 0);
            if (jb == R0 + rt * 16) {
                d.x = (lr == lg * 4 + 0) ? 0.f : d.x;
                d.y = (lr == lg * 4 + 1) ? 0.f : d.y;
                d.z = (lr == lg * 4 + 2) ? 0.f : d.z;
                d.w = (lr == lg * 4 + 3) ? 0.f : d.w;
            }
            s[rt][0] += exp2f(d.x);
            s[rt][1] += exp2f(d.y);
            s[rt][2] += exp2f(d.z);
            s[rt][3] += exp2f(d.w);
        }
        p0 = n0; p1 = n1;
    }

#pragma unroll
    for (int rt = 0; rt < 4; ++rt) {
#pragma unroll
        for (int off = 1; off < 16; off <<= 1) {
            s[rt][0] += __shfl_xor(s[rt][0], off, 64);
            s[rt][1] += __shfl_xor(s[rt][1], off, 64);
            s[rt][2] += __shfl_xor(s[rt][2], off, 64);
            s[rt][3] += __shfl_xor(s[rt][3], off, 64);
        }
        if (lr == 0) {
            float4 res = {s[rt][0], s[rt][1], s[rt][2], s[rt][3]};
            *(float4*)(s_part + (size_t)jseg * (BATCH * HW) + (size_t)b * HW +
                       R0 + rt * 16 + lg * 4) = res;
        }
    }
}

// ---------------------------------------------------------------------------
// Kernel C1 (MFMA): banded window attention weights.
// grid: B*HH*7 = 1792 blocks, 256 threads = 4 waves.
// ---------------------------------------------------------------------------
__global__ __launch_bounds__(256) void gcalc_mfma(
    const __hip_bfloat16* __restrict__ qh, const __hip_bfloat16* __restrict__ kh,
    const float* __restrict__ s_part, float* __restrict__ g)
{
    const int blk = blockIdx.x;            // ((b*64+h)*7 + dh)
    const int dh  = blk % 7;
    const int bh  = blk / 7;
    const int h   = bh & 63;
    const int b   = bh >> 6;
    const int tid = threadIdx.x;
    const int wv  = tid >> 6;
    const int l   = tid & 63;
    const int lg  = l >> 4, lr = l & 15;

    const int jh = min(max(h + dh - 3, 0), HH - 1);

    __shared__ float Dsh[64][65];
    __shared__ float rsh[64];

    if (tid < 64) {
        float s = 0.f;
        const size_t base = (size_t)b * HW + h * 64 + tid;
#pragma unroll
        for (int seg = 0; seg < NSEG; ++seg)
            s += s_part[(size_t)seg * (BATCH * HW) + base];
        rsh[tid] = 1.0f / s;
    }

    const short* qb = (const short*)(qh + ((size_t)b * HW + h * 64) * COUT);
    const short* kb = (const short*)(kh + ((size_t)b * HW + jh * 64) * COUT);

    const bf16x8 a0 = *(const bf16x8*)(qb + (size_t)(wv * 16 + lr) * COUT + lg * 8);
    const bf16x8 a1 = *(const bf16x8*)(qb + (size_t)(wv * 16 + lr) * COUT + 32 + lg * 8);

#pragma unroll
    for (int ct = 0; ct < 4; ++ct) {
        const bf16x8 b0 = *(const bf16x8*)(kb + (size_t)(ct * 16 + lr) * COUT + lg * 8);
        const bf16x8 b1 = *(const bf16x8*)(kb + (size_t)(ct * 16 + lr) * COUT + 32 + lg * 8);
        f32x4 d = {0.f, 0.f, 0.f, 0.f};
        d = __builtin_amdgcn_mfma_f32_16x16x32_bf16(a0, b0, d, 0, 0, 0);
        d = __builtin_amdgcn_mfma_f32_16x16x32_bf16(a1, b1, d, 0, 0, 0);
        const int row = wv * 16 + lg * 4;
        const int col = ct * 16 + lr;
        Dsh[row + 0][col] = d.x;
        Dsh[row + 1][col] = d.y;
        Dsh[row + 2][col] = d.z;
        Dsh[row + 3][col] = d.w;
    }
    __syncthreads();

    for (int e = tid; e < 64 * 7; e += 256) {
        const int w  = e / 7;
        const int tj = e - w * 7;
        const int jw = min(max(w + tj - 3, 0), WW - 1);
        const float num = (jh == h && jw == w) ? 1.0f : exp2f(Dsh[w][jw]);
        g[((size_t)b * HW + h * 64 + w) * NTAP + dh * 7 + tj] = num * rsh[w];
    }
}

// ---------------------------------------------------------------------------
// Kernel C2 (MFMA): out[b,p,o] = relu(bout[o] + sum_{t,c} gv[p][t*64+c]*W2[o,t,c])
// R7-proven structure + 3 fixes:
//  - ONE barrier per tap (double-buffered gvsh, write-next/barrier/read)
//  - B loads from coalesced W2p[t][kblk][o] (4 contiguous 256B runs per load)
//  - 1-deep register prefetch of next tap's v AND B fragments.
// grid: 512 blocks = (b, h, half-row), 256 threads = 4 waves; wave = o-tile.
// ---------------------------------------------------------------------------
__global__ __launch_bounds__(256) void out_mfma(
    const float* __restrict__ g, const float* __restrict__ v,
    const __hip_bfloat16* __restrict__ W2p, const float* __restrict__ bout,
    float* __restrict__ out)
{
    const int blk = blockIdx.x;          // 0..511
    const int b   = blk >> 7;            // 128 blocks per batch
    const int h   = (blk >> 1) & 63;
    const int w0  = (blk & 1) * 32;
    const int tid = threadIdx.x;
    const int wv  = tid >> 6;            // o-tile
    const int l   = tid & 63;
    const int lg  = l >> 4, lr = l & 15;

    __shared__ __attribute__((aligned(16))) __hip_bfloat16 gvsh[2][32][72];
    __shared__ float gsh[32][NTAP];

    const int row0 = b * HW + h * 64 + w0;
    for (int i = tid; i < 32 * NTAP; i += 256) {
        const int w = i / NTAP, t = i - w * NTAP;
        gsh[w][t] = g[(size_t)(row0 + w) * NTAP + t];
    }

    const int fw  = tid >> 4;            // staging pixel 0..15 (+16 for rep1)
    const int fc4 = tid & 15;            // float4 column
    const float* vb = v + ((size_t)b * HW) * COUT;

    auto vaddr = [&](int t, int rep) -> const float4* {
        const int dh = t / 7 - 3, dw = t - (t / 7) * 7 - 3;
        const int jh = min(max(h + dh, 0), HH - 1);
        const int jw = min(max(w0 + fw + rep * 16 + dw, 0), WW - 1);
        return (const float4*)(vb + (size_t)((jh << 6) + jw) * COUT) + fc4;
    };

    const short* wp = (const short*)W2p;
    // B fragment address: unit = (t*8 + sl*4 + lg)*64 + (wv*16 + lr)
    auto baddr = [&](int t, int sl) -> const bf16x8* {
        return (const bf16x8*)(wp + (size_t)(((t * 8 + sl * 4 + lg) << 6) + wv * 16 + lr) * 8);
    };

    // prefetch tap 0
    float4 vv0 = *vaddr(0, 0);
    float4 vv1 = *vaddr(0, 1);
    bf16x8 Bc0 = *baddr(0, 0);
    bf16x8 Bc1 = *baddr(0, 1);
    __syncthreads();                     // gsh ready

    f32x4 acc0 = {0.f, 0.f, 0.f, 0.f};
    f32x4 acc1 = {0.f, 0.f, 0.f, 0.f};

    for (int t = 0; t < NTAP; ++t) {
        // write gv for tap t from prefetched registers (buffer t&1)
        {
            const float g0 = gsh[fw][t], g1 = gsh[fw + 16][t];
            u16x4 pk0, pk1;
            pk0.x = __builtin_bit_cast(unsigned short, __float2bfloat16(vv0.x * g0));
            pk0.y = __builtin_bit_cast(unsigned short, __float2bfloat16(vv0.y * g0));
            pk0.z = __builtin_bit_cast(unsigned short, __float2bfloat16(vv0.z * g0));
            pk0.w = __builtin_bit_cast(unsigned short, __float2bfloat16(vv0.w * g0));
            pk1.x = __builtin_bit_cast(unsigned short, __float2bfloat16(vv1.x * g1));
            pk1.y = __builtin_bit_cast(unsigned short, __float2bfloat16(vv1.y * g1));
            pk1.z = __builtin_bit_cast(unsigned short, __float2bfloat16(vv1.z * g1));
            pk1.w = __builtin_bit_cast(unsigned short, __float2bfloat16(vv1.w * g1));
            *(u16x4*)(&gvsh[t & 1][fw][fc4 * 4])      = pk0;
            *(u16x4*)(&gvsh[t & 1][fw + 16][fc4 * 4]) = pk1;
        }

        // prefetch next tap (hidden under barrier + MFMA)
        float4 vn0, vn1;
        bf16x8 Bn0, Bn1;
        if (t != NTAP - 1) {
            vn0 = *vaddr(t + 1, 0);
            vn1 = *vaddr(t + 1, 1);
            Bn0 = *baddr(t + 1, 0);
            Bn1 = *baddr(t + 1, 1);
        }

        __syncthreads();
        const short* gsrc = (const short*)&gvsh[t & 1][0][0];
        const bf16x8 a00 = *(const bf16x8*)(gsrc + (size_t)lr * 72 + lg * 8);
        const bf16x8 a01 = *(const bf16x8*)(gsrc + (size_t)lr * 72 + 32 + lg * 8);
        const bf16x8 a10 = *(const bf16x8*)(gsrc + (size_t)(16 + lr) * 72 + lg * 8);
        const bf16x8 a11 = *(const bf16x8*)(gsrc + (size_t)(16 + lr) * 72 + 32 + lg * 8);
        acc0 = __builtin_amdgcn_mfma_f32_16x16x32_bf16(a00, Bc0, acc0, 0, 0, 0);
        acc0 = __builtin_amdgcn_mfma_f32_16x16x32_bf16(a01, Bc1, acc0, 0, 0, 0);
        acc1 = __builtin_amdgcn_mfma_f32_16x16x32_bf16(a10, Bc0, acc1, 0, 0, 0);
        acc1 = __builtin_amdgcn_mfma_f32_16x16x32_bf16(a11, Bc1, acc1, 0, 0, 0);

        vv0 = vn0; vv1 = vn1; Bc0 = Bn0; Bc1 = Bn1;
    }

    // epilogue: D[row=lg*4+j][col=lr] -> pixel w0 + rep*16 + lg*4 + j, o = wv*16+lr
    const int o  = wv * 16 + lr;
    const float bo = bout[o];
    float* obase = out + ((size_t)(b * COUT + o) * HW) + h * 64 + w0 + lg * 4;
    float4 r0, r1;
    r0.x = fmaxf(acc0.x + bo, 0.f); r0.y = fmaxf(acc0.y + bo, 0.f);
    r0.z = fmaxf(acc0.z + bo, 0.f); r0.w = fmaxf(acc0.w + bo, 0.f);
    r1.x = fmaxf(acc1.x + bo, 0.f); r1.y = fmaxf(acc1.y + bo, 0.f);
    r1.z = fmaxf(acc1.z + bo, 0.f); r1.w = fmaxf(acc1.w + bo, 0.f);
    *(float4*)obase        = r0;
    *(float4*)(obase + 16) = r1;
}

// ---------------------------------------------------------------------------
extern "C" void kernel_launch(void* const* d_in, const int* in_sizes, int n_in,
                              void* d_out, int out_size, void* d_ws, size_t ws_size,
                              hipStream_t stream)
{
    const float* x    = (const float*)d_in[0];
    const float* Wq   = (const float*)d_in[1];
    const float* bq   = (const float*)d_in[2];
    const float* Wk   = (const float*)d_in[3];
    const float* bk   = (const float*)d_in[4];
    const float* Wv   = (const float*)d_in[5];
    const float* bv   = (const float*)d_in[6];
    const float* Wout = (const float*)d_in[7];
    const float* bout = (const float*)d_in[8];
    float* out = (float*)d_out;

    // workspace layout (float units)
    float* ws      = (float*)d_ws;
    float* v       = ws;                                 // 1,048,576
    float* s_part  = v + (size_t)BATCH * HW * COUT;      // NSEG * B*HW
    float* g       = s_part + (size_t)NSEG * BATCH * HW; // 802,816
    float* bias192 = g + (size_t)BATCH * HW * NTAP;      // 192 (+pad)
    __hip_bfloat16* qh    = (__hip_bfloat16*)(bias192 + 256);
    __hip_bfloat16* kh    = qh + (size_t)BATCH * HW * COUT;
    __hip_bfloat16* W2p   = kh + (size_t)BATCH * HW * COUT;   // 200,704 bf16
    __hip_bfloat16* Wb192 = W2p + (size_t)NTAP * 8 * COUT * 8; // 49,152 bf16

    prep_kernel<<<(192 * 256 + NTAP * 8 * COUT * 8 + 255) / 256, 256, 0, stream>>>(
        Wq, bq, Wk, bk, Wv, bv, Wout, Wb192, bias192, W2p);
    qkv_mfma<<<BATCH * (HW / 16), 256, 0, stream>>>(x, Wb192, bias192, v, qh, kh);
    qk_stats_mfma<<<BATCH * 16 * NSEG, 256, 0, stream>>>(qh, kh, s_part);
    gcalc_mfma<<<BATCH * HH * 7, 256, 0, stream>>>(qh, kh, s_part, g);
    out_mfma<<<512, 256, 0, stream>>>(g, v, W2p, bout, out);
}

// Round 13
// 166.442 us; speedup vs baseline: 1.1877x; 1.0129x over previous
//
#include <hip/hip_runtime.h>
#include <hip/hip_bf16.h>
#include <math.h>

// Problem constants
#define BATCH 4
#define CIN   256
#define HH    64
#define WW    64
#define HW    4096      // HH*WW
#define COUT  64
#define KK    7
#define NTAP  49
#define NSEG  32        // j-segments in qk_stats (128 cols each)

// exp(d/8) == exp2(d * (log2e/8)); fold scale into bf16 q
#define QSCALE 0.18033688011112042f

typedef __attribute__((ext_vector_type(8))) short bf16x8;
typedef __attribute__((ext_vector_type(4))) float f32x4;
typedef __attribute__((ext_vector_type(4))) unsigned short u16x4;

// ---------------------------------------------------------------------------
// Prep: pack [Wq;Wk;Wv] -> Wb192 bf16 [192][256] + bias192, and
//       Wout (o,c,ti,tj) -> W2p bf16 [t][kblk(8)][o(64)][8]  (B-coalesced).
// ---------------------------------------------------------------------------
__global__ void prep_kernel(
    const float* __restrict__ Wq, const float* __restrict__ bq,
    const float* __restrict__ Wk, const float* __restrict__ bk,
    const float* __restrict__ Wv, const float* __restrict__ bv,
    const float* __restrict__ Wout,
    __hip_bfloat16* __restrict__ Wb192, float* __restrict__ bias192,
    __hip_bfloat16* __restrict__ W2p)
{
    const int idx = blockIdx.x * 256 + threadIdx.x;
    if (idx < 192 * 256) {
        const int row = idx >> 8, c = idx & 255;
        float wsrc;
        if (row < 64)       wsrc = Wq[row * 256 + c];
        else if (row < 128) wsrc = Wk[(row - 64) * 256 + c];
        else                wsrc = Wv[(row - 128) * 256 + c];
        Wb192[idx] = __float2bfloat16(wsrc);
        if (c == 0) {
            float bsrc;
            if (row < 64)       bsrc = bq[row];
            else if (row < 128) bsrc = bk[row - 64];
            else                bsrc = bv[row - 128];
            bias192[row] = bsrc;
        }
    } else if (idx < 192 * 256 + NTAP * 8 * COUT * 8) {
        const int j  = idx - 192 * 256;
        const int e  = j & 7;
        const int o  = (j >> 3) & 63;
        const int kb = (j >> 9) & 7;
        const int t  = j >> 12;
        const int c  = kb * 8 + e;
        W2p[j] = __float2bfloat16(Wout[((size_t)o * COUT + c) * NTAP + t]);
    }
}

// ---------------------------------------------------------------------------
// Kernel A (MFMA): QKV projection.  Writes v fp32 + qh (pre-scaled bf16) + kh.
// grid: B*HW/16 = 1024 blocks, 256 threads = 4 waves; wave owns 3 o-tiles.
// ---------------------------------------------------------------------------
__global__ __launch_bounds__(256) void qkv_mfma(
    const float* __restrict__ x,
    const __hip_bfloat16* __restrict__ Wb192, const float* __restrict__ bias192,
    float* __restrict__ v,
    __hip_bfloat16* __restrict__ qh, __hip_bfloat16* __restrict__ kh)
{
    const int blk = blockIdx.x;          // 0..1023
    const int b   = blk >> 8;
    const int p0  = (blk & 255) * 16;    // pixel within batch
    const int tid = threadIdx.x;
    const int wv  = tid >> 6;
    const int l   = tid & 63;
    const int lg  = l >> 4, lr = l & 15;

    __shared__ __attribute__((aligned(16))) __hip_bfloat16 xsh[16 * 256];

    // stage x[c][p0..p0+15] -> bf16 LDS transposed
    {
        const int c0 = tid >> 2;         // 0..63, +64/iter
        const int p4 = tid & 3;          // float4 index within row
        const float4* xb4 = (const float4*)(x + ((size_t)b * CIN) * HW + p0);
#pragma unroll
        for (int it = 0; it < 4; ++it) {
            const int cc = c0 + it * 64;
            const float4 xv = xb4[(size_t)cc * (HW / 4) + p4];
            __hip_bfloat16* dst = &xsh[((cc >> 3) * 16) * 8 + (cc & 7)];
            dst[(p4 * 4 + 0) * 8] = __float2bfloat16(xv.x);
            dst[(p4 * 4 + 1) * 8] = __float2bfloat16(xv.y);
            dst[(p4 * 4 + 2) * 8] = __float2bfloat16(xv.z);
            dst[(p4 * 4 + 3) * 8] = __float2bfloat16(xv.w);
        }
    }
    __syncthreads();

    f32x4 acc0 = {0.f,0.f,0.f,0.f}, acc1 = {0.f,0.f,0.f,0.f}, acc2 = {0.f,0.f,0.f,0.f};
    const short* wb  = (const short*)Wb192;
    const short* xs  = (const short*)xsh;

#pragma unroll
    for (int s = 0; s < 8; ++s) {
        const bf16x8 af = *(const bf16x8*)(xs + (size_t)(((s * 4 + lg) * 16 + lr)) * 8);
        const bf16x8 b0 = *(const bf16x8*)(wb + (size_t)((wv * 3 + 0) * 16 + lr) * 256 + s * 32 + lg * 8);
        const bf16x8 b1 = *(const bf16x8*)(wb + (size_t)((wv * 3 + 1) * 16 + lr) * 256 + s * 32 + lg * 8);
        const bf16x8 b2 = *(const bf16x8*)(wb + (size_t)((wv * 3 + 2) * 16 + lr) * 256 + s * 32 + lg * 8);
        acc0 = __builtin_amdgcn_mfma_f32_16x16x32_bf16(af, b0, acc0, 0, 0, 0);
        acc1 = __builtin_amdgcn_mfma_f32_16x16x32_bf16(af, b1, acc1, 0, 0, 0);
        acc2 = __builtin_amdgcn_mfma_f32_16x16x32_bf16(af, b2, acc2, 0, 0, 0);
    }

    // epilogue: row = pixel = p0 + lg*4 + j ; col = o = (otile&3)*16 + lr
    f32x4 accs[3] = {acc0, acc1, acc2};
#pragma unroll
    for (int i = 0; i < 3; ++i) {
        const int otile = wv * 3 + i;
        const int kind  = otile >> 2;            // 0=q 1=k 2=v
        const int o     = (otile & 3) * 16 + lr;
        const float bias = bias192[otile * 16 + lr];
#pragma unroll
        for (int j = 0; j < 4; ++j) {
            const int p = p0 + lg * 4 + j;
            const size_t addr = ((size_t)b * HW + p) * (size_t)COUT + o;
            const float val = accs[i][j] + bias;
            if (kind == 0)      { qh[addr] = __float2bfloat16(val * QSCALE); }
            else if (kind == 1) { kh[addr] = __float2bfloat16(val); }
            else                { v[addr] = val; }
        }
    }
}

// ---------------------------------------------------------------------------
// Kernel B (MFMA): per-row sum of exp(qk/8), diag forced to logit 0.
// grid: 4 b x 16 panels(256 rows) x 32 jsegs(128 cols) = 2048 blocks
// (8 blocks/CU -> 32 waves/CU, full occupancy).
// Wave owns 64 Q-rows (4 row-tiles in registers); 2-DEEP K prefetch so
// ~2 iterations (~300 cyc) of issue time cover the L2 load latency.
// ---------------------------------------------------------------------------
__global__ __launch_bounds__(256) void qk_stats_mfma(
    const __hip_bfloat16* __restrict__ qh, const __hip_bfloat16* __restrict__ kh,
    float* __restrict__ s_part)
{
    const int blk   = blockIdx.x;           // 0..2047
    const int b     = blk >> 9;             // 512 blocks per batch
    const int panel = (blk >> 5) & 15;      // 256-row panel
    const int jseg  = blk & 31;             // 128-col segment
    const int tid   = threadIdx.x;
    const int w     = tid >> 6;
    const int l     = tid & 63;
    const int lg    = l >> 4;
    const int lr    = l & 15;
    const int R0    = panel * 256 + w * 64; // wave's first Q row

    const short* qb = (const short*)(qh + ((size_t)b * HW) * COUT);
    const short* kb = (const short*)(kh + ((size_t)b * HW) * COUT);

    // A fragments: 4 row-tiles x 2 k-slices
    bf16x8 a[4][2];
#pragma unroll
    for (int rt = 0; rt < 4; ++rt) {
        a[rt][0] = *(const bf16x8*)(qb + (size_t)(R0 + rt * 16 + lr) * COUT + lg * 8);
        a[rt][1] = *(const bf16x8*)(qb + (size_t)(R0 + rt * 16 + lr) * COUT + 32 + lg * 8);
    }

    float s[4][4];
#pragma unroll
    for (int rt = 0; rt < 4; ++rt)
#pragma unroll
        for (int i = 0; i < 4; ++i) s[rt][i] = 0.f;

    const int j0 = jseg * 128;
    const short* kptr = kb + (size_t)(j0 + lr) * COUT + lg * 8;

    // 2-deep software pipeline: pa = iter it, pb = iter it+1, load it+2
    bf16x8 pa0 = *(const bf16x8*)(kptr);
    bf16x8 pa1 = *(const bf16x8*)(kptr + 32);
    bf16x8 pb0 = *(const bf16x8*)(kptr + 16 * COUT);
    bf16x8 pb1 = *(const bf16x8*)(kptr + 16 * COUT + 32);
    kptr += 32 * COUT;

    for (int it = 0; it < 8; ++it) {
        bf16x8 n0, n1;
        if (it < 6) {
            n0 = *(const bf16x8*)(kptr);
            n1 = *(const bf16x8*)(kptr + 32);
            kptr += 16 * COUT;
        }
        const int jb = j0 + it * 16;
#pragma unroll
        for (int rt = 0; rt < 4; ++rt) {
            f32x4 d = {0.f, 0.f, 0.f, 0.f};
            d = __builtin_amdgcn_mfma_f32_16x16x32_bf16(a[rt][0], pa0, d, 0, 0, 0);
            d = __builtin_amdgcn_mfma_f32_16x16x32_bf16(a[rt][1], pa1, d, 0, 0, 0);
            if (jb == R0 + rt * 16) {
                d.x = (lr == lg * 4 + 0) ? 0.f : d.x;
                d.y = (lr == lg * 4 + 1) ? 0.f : d.y;
                d.z = (lr == lg * 4 + 2) ? 0.f : d.z;
                d.w = (lr == lg * 4 + 3) ? 0.f : d.w;
            }
            s[rt][0] += exp2f(d.x);
            s[rt][1] += exp2f(d.y);
            s[rt][2] += exp2f(d.z);
            s[rt][3] += exp2f(d.w);
        }
        pa0 = pb0; pa1 = pb1;
        pb0 = n0;  pb1 = n1;
    }

    // reduce across the 16 lanes sharing a row-group, per row-tile
#pragma unroll
    for (int rt = 0; rt < 4; ++rt) {
#pragma unroll
        for (int off = 1; off < 16; off <<= 1) {
            s[rt][0] += __shfl_xor(s[rt][0], off, 64);
            s[rt][1] += __shfl_xor(s[rt][1], off, 64);
            s[rt][2] += __shfl_xor(s[rt][2], off, 64);
            s[rt][3] += __shfl_xor(s[rt][3], off, 64);
        }
        if (lr == 0) {
            float4 res = {s[rt][0], s[rt][1], s[rt][2], s[rt][3]};
            *(float4*)(s_part + (size_t)jseg * (BATCH * HW) + (size_t)b * HW +
                       R0 + rt * 16 + lg * 4) = res;
        }
    }
}

// ---------------------------------------------------------------------------
// Kernel C1 (MFMA): banded window attention weights.
// grid: B*HH*7 = 1792 blocks, 256 threads = 4 waves.
// ---------------------------------------------------------------------------
__global__ __launch_bounds__(256) void gcalc_mfma(
    const __hip_bfloat16* __restrict__ qh, const __hip_bfloat16* __restrict__ kh,
    const float* __restrict__ s_part, float* __restrict__ g)
{
    const int blk = blockIdx.x;            // ((b*64+h)*7 + dh)
    const int dh  = blk % 7;
    const int bh  = blk / 7;
    const int h   = bh & 63;
    const int b   = bh >> 6;
    const int tid = threadIdx.x;
    const int wv  = tid >> 6;
    const int l   = tid & 63;
    const int lg  = l >> 4, lr = l & 15;

    const int jh = min(max(h + dh - 3, 0), HH - 1);

    __shared__ float Dsh[64][65];
    __shared__ float rsh[64];

    if (tid < 64) {
        float s = 0.f;
        const size_t base = (size_t)b * HW + h * 64 + tid;
#pragma unroll
        for (int seg = 0; seg < NSEG; ++seg)
            s += s_part[(size_t)seg * (BATCH * HW) + base];
        rsh[tid] = 1.0f / s;
    }

    const short* qb = (const short*)(qh + ((size_t)b * HW + h * 64) * COUT);
    const short* kb = (const short*)(kh + ((size_t)b * HW + jh * 64) * COUT);

    const bf16x8 a0 = *(const bf16x8*)(qb + (size_t)(wv * 16 + lr) * COUT + lg * 8);
    const bf16x8 a1 = *(const bf16x8*)(qb + (size_t)(wv * 16 + lr) * COUT + 32 + lg * 8);

#pragma unroll
    for (int ct = 0; ct < 4; ++ct) {
        const bf16x8 b0 = *(const bf16x8*)(kb + (size_t)(ct * 16 + lr) * COUT + lg * 8);
        const bf16x8 b1 = *(const bf16x8*)(kb + (size_t)(ct * 16 + lr) * COUT + 32 + lg * 8);
        f32x4 d = {0.f, 0.f, 0.f, 0.f};
        d = __builtin_amdgcn_mfma_f32_16x16x32_bf16(a0, b0, d, 0, 0, 0);
        d = __builtin_amdgcn_mfma_f32_16x16x32_bf16(a1, b1, d, 0, 0, 0);
        const int row = wv * 16 + lg * 4;
        const int col = ct * 16 + lr;
        Dsh[row + 0][col] = d.x;
        Dsh[row + 1][col] = d.y;
        Dsh[row + 2][col] = d.z;
        Dsh[row + 3][col] = d.w;
    }
    __syncthreads();

    for (int e = tid; e < 64 * 7; e += 256) {
        const int w  = e / 7;
        const int tj = e - w * 7;
        const int jw = min(max(w + tj - 3, 0), WW - 1);
        const float num = (jh == h && jw == w) ? 1.0f : exp2f(Dsh[w][jw]);
        g[((size_t)b * HW + h * 64 + w) * NTAP + dh * 7 + tj] = num * rsh[w];
    }
}

// ---------------------------------------------------------------------------
// Kernel C2 (MFMA): out[b,p,o] = relu(bout[o] + sum_{t,c} gv[p][t*64+c]*W2[o,t,c])
// R7-proven structure: one barrier per tap (dbuf gvsh), coalesced W2p B loads,
// 1-deep register prefetch of next tap's v AND B fragments.
// grid: 512 blocks = (b, h, half-row), 256 threads = 4 waves; wave = o-tile.
// ---------------------------------------------------------------------------
__global__ __launch_bounds__(256) void out_mfma(
    const float* __restrict__ g, const float* __restrict__ v,
    const __hip_bfloat16* __restrict__ W2p, const float* __restrict__ bout,
    float* __restrict__ out)
{
    const int blk = blockIdx.x;          // 0..511
    const int b   = blk >> 7;            // 128 blocks per batch
    const int h   = (blk >> 1) & 63;
    const int w0  = (blk & 1) * 32;
    const int tid = threadIdx.x;
    const int wv  = tid >> 6;            // o-tile
    const int l   = tid & 63;
    const int lg  = l >> 4, lr = l & 15;

    __shared__ __attribute__((aligned(16))) __hip_bfloat16 gvsh[2][32][72];
    __shared__ float gsh[32][NTAP];

    const int row0 = b * HW + h * 64 + w0;
    for (int i = tid; i < 32 * NTAP; i += 256) {
        const int w = i / NTAP, t = i - w * NTAP;
        gsh[w][t] = g[(size_t)(row0 + w) * NTAP + t];
    }

    const int fw  = tid >> 4;            // staging pixel 0..15 (+16 for rep1)
    const int fc4 = tid & 15;            // float4 column
    const float* vb = v + ((size_t)b * HW) * COUT;

    auto vaddr = [&](int t, int rep) -> const float4* {
        const int dh = t / 7 - 3, dw = t - (t / 7) * 7 - 3;
        const int jh = min(max(h + dh, 0), HH - 1);
        const int jw = min(max(w0 + fw + rep * 16 + dw, 0), WW - 1);
        return (const float4*)(vb + (size_t)((jh << 6) + jw) * COUT) + fc4;
    };

    const short* wp = (const short*)W2p;
    auto baddr = [&](int t, int sl) -> const bf16x8* {
        return (const bf16x8*)(wp + (size_t)(((t * 8 + sl * 4 + lg) << 6) + wv * 16 + lr) * 8);
    };

    // prefetch tap 0
    float4 vv0 = *vaddr(0, 0);
    float4 vv1 = *vaddr(0, 1);
    bf16x8 Bc0 = *baddr(0, 0);
    bf16x8 Bc1 = *baddr(0, 1);
    __syncthreads();                     // gsh ready

    f32x4 acc0 = {0.f, 0.f, 0.f, 0.f};
    f32x4 acc1 = {0.f, 0.f, 0.f, 0.f};

    for (int t = 0; t < NTAP; ++t) {
        {
            const float g0 = gsh[fw][t], g1 = gsh[fw + 16][t];
            u16x4 pk0, pk1;
            pk0.x = __builtin_bit_cast(unsigned short, __float2bfloat16(vv0.x * g0));
            pk0.y = __builtin_bit_cast(unsigned short, __float2bfloat16(vv0.y * g0));
            pk0.z = __builtin_bit_cast(unsigned short, __float2bfloat16(vv0.z * g0));
            pk0.w = __builtin_bit_cast(unsigned short, __float2bfloat16(vv0.w * g0));
            pk1.x = __builtin_bit_cast(unsigned short, __float2bfloat16(vv1.x * g1));
            pk1.y = __builtin_bit_cast(unsigned short, __float2bfloat16(vv1.y * g1));
            pk1.z = __builtin_bit_cast(unsigned short, __float2bfloat16(vv1.z * g1));
            pk1.w = __builtin_bit_cast(unsigned short, __float2bfloat16(vv1.w * g1));
            *(u16x4*)(&gvsh[t & 1][fw][fc4 * 4])      = pk0;
            *(u16x4*)(&gvsh[t & 1][fw + 16][fc4 * 4]) = pk1;
        }

        float4 vn0, vn1;
        bf16x8 Bn0, Bn1;
        if (t != NTAP - 1) {
            vn0 = *vaddr(t + 1, 0);
            vn1 = *vaddr(t + 1, 1);
            Bn0 = *baddr(t + 1, 0);
            Bn1 = *baddr(t + 1, 1);
        }

        __syncthreads();
        const short* gsrc = (const short*)&gvsh[t & 1][0][0];
        const bf16x8 a00 = *(const bf16x8*)(gsrc + (size_t)lr * 72 + lg * 8);
        const bf16x8 a01 = *(const bf16x8*)(gsrc + (size_t)lr * 72 + 32 + lg * 8);
        const bf16x8 a10 = *(const bf16x8*)(gsrc + (size_t)(16 + lr) * 72 + lg * 8);
        const bf16x8 a11 = *(const bf16x8*)(gsrc + (size_t)(16 + lr) * 72 + 32 + lg * 8);
        acc0 = __builtin_amdgcn_mfma_f32_16x16x32_bf16(a00, Bc0, acc0, 0, 0, 0);
        acc0 = __builtin_amdgcn_mfma_f32_16x16x32_bf16(a01, Bc1, acc0, 0, 0, 0);
        acc1 = __builtin_amdgcn_mfma_f32_16x16x32_bf16(a10, Bc0, acc1, 0, 0, 0);
        acc1 = __builtin_amdgcn_mfma_f32_16x16x32_bf16(a11, Bc1, acc1, 0, 0, 0);

        vv0 = vn0; vv1 = vn1; Bc0 = Bn0; Bc1 = Bn1;
    }

    const int o  = wv * 16 + lr;
    const float bo = bout[o];
    float* obase = out + ((size_t)(b * COUT + o) * HW) + h * 64 + w0 + lg * 4;
    float4 r0, r1;
    r0.x = fmaxf(acc0.x + bo, 0.f); r0.y = fmaxf(acc0.y + bo, 0.f);
    r0.z = fmaxf(acc0.z + bo, 0.f); r0.w = fmaxf(acc0.w + bo, 0.f);
    r1.x = fmaxf(acc1.x + bo, 0.f); r1.y = fmaxf(acc1.y + bo, 0.f);
    r1.z = fmaxf(acc1.z + bo, 0.f); r1.w = fmaxf(acc1.w + bo, 0.f);
    *(float4*)obase        = r0;
    *(float4*)(obase + 16) = r1;
}

// ---------------------------------------------------------------------------
extern "C" void kernel_launch(void* const* d_in, const int* in_sizes, int n_in,
                              void* d_out, int out_size, void* d_ws, size_t ws_size,
                              hipStream_t stream)
{
    const float* x    = (const float*)d_in[0];
    const float* Wq   = (const float*)d_in[1];
    const float* bq   = (const float*)d_in[2];
    const float* Wk   = (const float*)d_in[3];
    const float* bk   = (const float*)d_in[4];
    const float* Wv   = (const float*)d_in[5];
    const float* bv   = (const float*)d_in[6];
    const float* Wout = (const float*)d_in[7];
    const float* bout = (const float*)d_in[8];
    float* out = (float*)d_out;

    // workspace layout (float units)
    float* ws      = (float*)d_ws;
    float* v       = ws;                                 // 1,048,576
    float* s_part  = v + (size_t)BATCH * HW * COUT;      // NSEG * B*HW
    float* g       = s_part + (size_t)NSEG * BATCH * HW; // 802,816
    float* bias192 = g + (size_t)BATCH * HW * NTAP;      // 192 (+pad)
    __hip_bfloat16* qh    = (__hip_bfloat16*)(bias192 + 256);
    __hip_bfloat16* kh    = qh + (size_t)BATCH * HW * COUT;
    __hip_bfloat16* W2p   = kh + (size_t)BATCH * HW * COUT;   // 200,704 bf16
    __hip_bfloat16* Wb192 = W2p + (size_t)NTAP * 8 * COUT * 8; // 49,152 bf16

    prep_kernel<<<(192 * 256 + NTAP * 8 * COUT * 8 + 255) / 256, 256, 0, stream>>>(
        Wq, bq, Wk, bk, Wv, bv, Wout, Wb192, bias192, W2p);
    qkv_mfma<<<BATCH * (HW / 16), 256, 0, stream>>>(x, Wb192, bias192, v, qh, kh);
    qk_stats_mfma<<<BATCH * 16 * NSEG, 256, 0, stream>>>(qh, kh, s_part);
    gcalc_mfma<<<BATCH * HH * 7, 256, 0, stream>>>(qh, kh, s_part, g);
    out_mfma<<<512, 256, 0, stream>>>(g, v, W2p, bout, out);
}